// Round 5
// baseline (480.697 us; speedup 1.0000x reference)
//
#include <hip/hip_runtime.h>
#include <hip/hip_bf16.h>

#define NEDGE 800000
#define NNODE 50000
#define NBATCH (NEDGE / 128)   // 6250 batches of 128 edges (8 waves x 16 edges)

typedef __attribute__((ext_vector_type(8))) short bf16x8;
typedef __attribute__((ext_vector_type(4))) float f32x4;
typedef __attribute__((ext_vector_type(4))) float f4;

static __device__ __forceinline__ unsigned short f2bf(float f) {
    union { float f; unsigned u; } v; v.f = f;
    unsigned r = v.u + 0x7fffu + ((v.u >> 16) & 1u);   // RNE
    return (unsigned short)(r >> 16);
}

// DPP-based sum allreduce over each 16-lane quarter (DPP "row" = 16 lanes).
template<int CTRL>
static __device__ __forceinline__ float dppadd(float x) {
    int y = __builtin_amdgcn_update_dpp(0, __builtin_bit_cast(int, x), CTRL, 0xf, 0xf, true);
    return x + __builtin_bit_cast(float, y);
}
static __device__ __forceinline__ float allred16(float x) {
    x = dppadd<0xB1>(x);    // quad_perm xor1
    x = dppadd<0x4E>(x);    // quad_perm xor2
    x = dppadd<0x141>(x);   // row_half_mirror
    x = dppadd<0x140>(x);   // row_mirror
    return x;
}

static __device__ __forceinline__ unsigned cvt_pk_bf16(float lo, float hi) {
    unsigned r;
    asm("v_cvt_pk_bf16_f32 %0, %1, %2" : "=v"(r) : "v"(lo), "v"(hi));
    return r;
}

// LDS budget: wfrag 32768 + overlay 9216 = 41984 B -> 3 blocks/CU under the
// empirical ~128KB usable pool (R4 evidence: 52224B gave only 2 resident).
union Ovl {
    float bias[4][64];                 // valid until cached to regs (barrier-protected)
    unsigned short o[8][8][72];        // per-wave 8-row O tile (two-pass transpose)
};

__global__ __launch_bounds__(512, 4) void nti_main(
    const float* __restrict__ x_cen, const float* __restrict__ x_nei,
    const int* __restrict__ eidx,
    const float* __restrict__ ln_g, const float* __restrict__ ln_b,
    const float* __restrict__ Wq, const float* __restrict__ bq,
    const float* __restrict__ Wk, const float* __restrict__ bk,
    const float* __restrict__ Wv, const float* __restrict__ bv,
    const float* __restrict__ Wo, const float* __restrict__ bo,
    float* __restrict__ outsum, float* __restrict__ cnt)
{
    __shared__ __align__(16) unsigned short wfrag[32][64][8];   // 32 KB
    __shared__ __align__(16) Ovl ovl;                            // 9 KB

    const int tid = threadIdx.x;

    // ---- one-time weight staging: fold LN affine into Wq/Wk/Wv, D^-0.5 into Wq ----
    if (tid < 256) {
        const int mat = tid >> 6, c = tid & 63;
        const float* W  = (mat == 0) ? Wq : (mat == 1) ? Wk : (mat == 2) ? Wv : Wo;
        const float* bb = (mat == 0) ? bq : (mat == 1) ? bk : (mat == 2) ? bv : bo;
        const float qs = (mat == 0) ? 0.25f : 1.0f;
        float bias = bb[c];
        for (int j = 0; j < 64; ++j) {
            float w = W[c * 64 + j];
            if (mat < 3) { bias += ln_b[j] * w; w *= ln_g[j]; }
            const int kh = j >> 5, ln = ((j >> 3) & 3) * 16 + (c & 15), i = j & 7;
            wfrag[mat * 8 + kh * 4 + (c >> 4)][ln][i] = f2bf(w * qs);
        }
        ovl.bias[mat][c] = bias * qs;
    }
    __syncthreads();

    const int wid = tid >> 6, lane = tid & 63;
    const int qg = lane >> 4;        // quarter / k-chunk
    const int rt = lane & 15;        // row within M-tile
    const int tok = rt & 3;          // token type of this row
    const int em  = rt >> 2;         // edge within M-tile
    const float ac = (tok == 0 || tok == 2) ? 1.f : (tok == 3) ? -1.f : 0.f;
    const float an = (tok == 0) ? 0.f : 1.f;

    // loop-invariant biases -> registers, then barrier before obuf overlays bias
    float biasq[4], biask[4], biasv[4], biaso[4];
    #pragma unroll
    for (int nt = 0; nt < 4; ++nt) {
        biasq[nt] = ovl.bias[0][nt * 16 + rt];
        biask[nt] = ovl.bias[1][nt * 16 + rt];
        biasv[nt] = ovl.bias[2][nt * 16 + rt];
        biaso[nt] = ovl.bias[3][nt * 16 + rt];
    }
    __syncthreads();   // protect bias reads from obuf overwrites

    for (int batch = blockIdx.x; batch < NBATCH; batch += gridDim.x) {
        const int ebase = batch * 128 + wid * 16;

        // prefetch scatter targets for both passes (lanes qg>=2 duplicate qg&1)
        int tg[2][4];
        #pragma unroll
        for (int p = 0; p < 2; ++p)
            #pragma unroll
            for (int r = 0; r < 4; ++r)
                tg[p][r] = eidx[NEDGE + ebase + p * 8 + (qg & 1) * 4 + r];

        // ---- phase 1: build A-fragments (LN'd tokens) for 4 M-tiles = 16 edges ----
        bf16x8 af[4][2];
        #pragma unroll
        for (int m = 0; m < 4; ++m) {
            const int eg = ebase + m * 4 + em;
            const f4* pc4 = (const f4*)(x_cen + (size_t)eg * 64);
            const f4* pn4 = (const f4*)(x_nei + (size_t)eg * 64);
            f4 a0 = pc4[qg * 2], a1 = pc4[qg * 2 + 1], a2 = pc4[8 + qg * 2], a3 = pc4[8 + qg * 2 + 1];
            f4 b0 = pn4[qg * 2], b1 = pn4[qg * 2 + 1], b2 = pn4[8 + qg * 2], b3 = pn4[8 + qg * 2 + 1];
            float tv[16];
            #pragma unroll
            for (int i = 0; i < 4; ++i) {
                tv[i]      = ac * a0[i] + an * b0[i];
                tv[4 + i]  = ac * a1[i] + an * b1[i];
                tv[8 + i]  = ac * a2[i] + an * b2[i];
                tv[12 + i] = ac * a3[i] + an * b3[i];
            }
            float s = 0.f, ss = 0.f;
            #pragma unroll
            for (int i = 0; i < 16; ++i) { s += tv[i]; ss = fmaf(tv[i], tv[i], ss); }
            s  += __shfl_xor(s, 16, 64);  ss += __shfl_xor(ss, 16, 64);
            s  += __shfl_xor(s, 32, 64);  ss += __shfl_xor(ss, 32, 64);
            const float mu  = s * 0.015625f;
            const float var = fmaf(ss, 0.015625f, -mu * mu);
            const float rs  = rsqrtf(var + 1e-5f);
            const float nmrs = -mu * rs;
            #pragma unroll
            for (int kh = 0; kh < 2; ++kh) {
                union { bf16x8 v; unsigned u[4]; } pk;
                #pragma unroll
                for (int pp = 0; pp < 4; ++pp) {
                    float lo = fmaf(tv[kh * 8 + 2 * pp],     rs, nmrs);
                    float hi = fmaf(tv[kh * 8 + 2 * pp + 1], rs, nmrs);
                    pk.u[pp] = cvt_pk_bf16(lo, hi);
                }
                af[m][kh] = pk.v;
            }
        }

        // ---- two passes of 8 edges: phase2 (q/k/v+softmax) -> phase3 (Wo) -> scatter ----
        #pragma unroll
        for (int p = 0; p < 2; ++p) {
            // phase 2
            #pragma unroll
            for (int nt = 0; nt < 4; ++nt) {
                bf16x8 wq0 = *(const bf16x8*)&wfrag[0  + nt][lane][0];
                bf16x8 wq1 = *(const bf16x8*)&wfrag[4  + nt][lane][0];
                bf16x8 wk0 = *(const bf16x8*)&wfrag[8  + nt][lane][0];
                bf16x8 wk1 = *(const bf16x8*)&wfrag[12 + nt][lane][0];
                bf16x8 wv0 = *(const bf16x8*)&wfrag[16 + nt][lane][0];
                bf16x8 wv1 = *(const bf16x8*)&wfrag[20 + nt][lane][0];
                #pragma unroll
                for (int mm = 0; mm < 2; ++mm) {
                    const int m = 2 * p + mm;
                    f32x4 aq = {biasq[nt], biasq[nt], biasq[nt], biasq[nt]};
                    f32x4 ak = {biask[nt], biask[nt], biask[nt], biask[nt]};
                    f32x4 av = {biasv[nt], biasv[nt], biasv[nt], biasv[nt]};
                    aq = __builtin_amdgcn_mfma_f32_16x16x32_bf16(af[m][0], wq0, aq, 0, 0, 0);
                    aq = __builtin_amdgcn_mfma_f32_16x16x32_bf16(af[m][1], wq1, aq, 0, 0, 0);
                    ak = __builtin_amdgcn_mfma_f32_16x16x32_bf16(af[m][0], wk0, ak, 0, 0, 0);
                    ak = __builtin_amdgcn_mfma_f32_16x16x32_bf16(af[m][1], wk1, ak, 0, 0, 0);
                    av = __builtin_amdgcn_mfma_f32_16x16x32_bf16(af[m][0], wv0, av, 0, 0, 0);
                    av = __builtin_amdgcn_mfma_f32_16x16x32_bf16(af[m][1], wv1, av, 0, 0, 0);
                    float p0 = allred16(aq[0] * ak[0]);
                    float p1 = allred16(aq[0] * ak[1]);
                    float p2 = allred16(aq[0] * ak[2]);
                    float p3 = allred16(aq[0] * ak[3]);
                    const float mx = fmaxf(fmaxf(p0, p1), fmaxf(p2, p3));
                    const float e0 = __expf(p0 - mx), e1 = __expf(p1 - mx);
                    const float e2 = __expf(p2 - mx), e3 = __expf(p3 - mx);
                    const float inv = 1.f / (e0 + e1 + e2 + e3);
                    const float ov = (e0 * av[0] + e1 * av[1] + e2 * av[2] + e3 * av[3]) * inv;
                    ovl.o[wid][mm * 4 + qg][nt * 16 + rt] = f2bf(ov);   // local row
                }
            }

            // residual prefetch (overlaps phase-3 LDS+MFMA); qg>=2 duplicates
            float res[4][4];
            #pragma unroll
            for (int nt = 0; nt < 4; ++nt) {
                const int col = nt * 16 + rt;
                #pragma unroll
                for (int r = 0; r < 4; ++r)
                    res[nt][r] = x_cen[(size_t)(ebase + p * 8 + (qg & 1) * 4 + r) * 64 + col];
            }

            // phase 3: Wo projection; A rows 0-7 valid (rows 8-15 duplicate, discarded)
            bf16x8 oa0 = *(const bf16x8*)&ovl.o[wid][rt & 7][qg * 8];
            bf16x8 oa1 = *(const bf16x8*)&ovl.o[wid][rt & 7][32 + qg * 8];
            f32x4 accO[4];
            #pragma unroll
            for (int nt = 0; nt < 4; ++nt) {
                bf16x8 wo0 = *(const bf16x8*)&wfrag[24 + nt][lane][0];
                bf16x8 wo1 = *(const bf16x8*)&wfrag[28 + nt][lane][0];
                f32x4 acc = {biaso[nt], biaso[nt], biaso[nt], biaso[nt]};
                acc = __builtin_amdgcn_mfma_f32_16x16x32_bf16(oa0, wo0, acc, 0, 0, 0);
                acc = __builtin_amdgcn_mfma_f32_16x16x32_bf16(oa1, wo1, acc, 0, 0, 0);
                accO[nt] = acc;
            }

            // epilogue: D rows 0-7 = lanes qg<2 hold the 8 valid edges
            if (qg < 2) {
                #pragma unroll
                for (int nt = 0; nt < 4; ++nt) {
                    const int col = nt * 16 + rt;
                    #pragma unroll
                    for (int r = 0; r < 4; ++r) {
                        const float val = accO[nt][r] + res[nt][r];
                        atomicAdd(outsum + (size_t)tg[p][r] * 64 + col, val);
                    }
                }
                if (rt == 0) {
                    #pragma unroll
                    for (int r = 0; r < 4; ++r) atomicAdd(cnt + tg[p][r], 1.0f);
                }
            }
        }
    }
}

__global__ void nti_div(float* __restrict__ out, const float* __restrict__ cnt) {
    int i = blockIdx.x * 256 + threadIdx.x;
    if (i < NNODE * 64) {
        float c = cnt[i >> 6];
        out[i] = out[i] / fmaxf(c, 1.0f);
    }
}

extern "C" void kernel_launch(void* const* d_in, const int* in_sizes, int n_in,
                              void* d_out, int out_size, void* d_ws, size_t ws_size,
                              hipStream_t stream) {
    const float* x_cen = (const float*)d_in[0];
    const float* x_nei = (const float*)d_in[1];
    const int*   eidx  = (const int*)d_in[2];
    const float* ln_g  = (const float*)d_in[3];
    const float* ln_b  = (const float*)d_in[4];
    const float* Wq = (const float*)d_in[5];  const float* bq = (const float*)d_in[6];
    const float* Wk = (const float*)d_in[7];  const float* bk = (const float*)d_in[8];
    const float* Wv = (const float*)d_in[9];  const float* bv = (const float*)d_in[10];
    const float* Wo = (const float*)d_in[11]; const float* bo = (const float*)d_in[12];
    float* out = (float*)d_out;
    float* cnt = (float*)d_ws;

    hipMemsetAsync(d_out, 0, (size_t)NNODE * 64 * sizeof(float), stream);
    hipMemsetAsync(d_ws,  0, (size_t)NNODE * sizeof(float), stream);
    nti_main<<<768, 512, 0, stream>>>(x_cen, x_nei, eidx, ln_g, ln_b,
                                      Wq, bq, Wk, bk, Wv, bv, Wo, bo, out, cnt);
    nti_div<<<(NNODE * 64 + 255) / 256, 256, 0, stream>>>(out, cnt);
}

// Round 6
// 285.744 us; speedup vs baseline: 1.6823x; 1.6823x over previous
//
#include <hip/hip_runtime.h>
#include <hip/hip_bf16.h>

#define NEDGE 800000
#define NNODE 50000
#define NBATCH (NEDGE / 128)   // 6250 batches of 128 edges (8 waves x 16 edges)

typedef __attribute__((ext_vector_type(8))) short bf16x8;
typedef __attribute__((ext_vector_type(4))) float f32x4;
typedef __attribute__((ext_vector_type(4))) float f4;

static __device__ __forceinline__ unsigned short f2bf(float f) {
    union { float f; unsigned u; } v; v.f = f;
    unsigned r = v.u + 0x7fffu + ((v.u >> 16) & 1u);   // RNE
    return (unsigned short)(r >> 16);
}

// DPP-based sum allreduce over each 16-lane quarter (DPP "row" = 16 lanes).
template<int CTRL>
static __device__ __forceinline__ float dppadd(float x) {
    int y = __builtin_amdgcn_update_dpp(0, __builtin_bit_cast(int, x), CTRL, 0xf, 0xf, true);
    return x + __builtin_bit_cast(float, y);
}
static __device__ __forceinline__ float allred16(float x) {
    x = dppadd<0xB1>(x);    // quad_perm xor1
    x = dppadd<0x4E>(x);    // quad_perm xor2
    x = dppadd<0x141>(x);   // row_half_mirror
    x = dppadd<0x140>(x);   // row_mirror
    return x;
}

static __device__ __forceinline__ unsigned cvt_pk_bf16(float lo, float hi) {
    unsigned r;
    asm("v_cvt_pk_bf16_f32 %0, %1, %2" : "=v"(r) : "v"(lo), "v"(hi));
    return r;
}

// Occupancy note (R2-R5 evidence): residency is 2 blocks/CU regardless of LDS
// (42KB vs 52KB identical) -> cap is the unified VGPR+acc register file
// (~128/wave -> 4 waves/SIMD). Therefore grid MUST be 512 (= exact resident
// capacity); grid 768 creates a second generation at 1 block/CU (R4: +24us).
__global__ __launch_bounds__(512, 4) void nti_main(
    const float* __restrict__ x_cen, const float* __restrict__ x_nei,
    const int* __restrict__ eidx,
    const float* __restrict__ ln_g, const float* __restrict__ ln_b,
    const float* __restrict__ Wq, const float* __restrict__ bq,
    const float* __restrict__ Wk, const float* __restrict__ bk,
    const float* __restrict__ Wv, const float* __restrict__ bv,
    const float* __restrict__ Wo, const float* __restrict__ bo,
    float* __restrict__ outsum, float* __restrict__ cnt)
{
    // B-fragments: [mat*8 + kh*4 + nt][lane][8 bf16]  (q=0,k=1,v=2,o=3)
    __shared__ __align__(16) unsigned short wfrag[32][64][8];   // 32 KB
    __shared__ float bias_s[4][64];                             // 1 KB
    // per-wave O tile: 16 rows (edges) x 64 cols, pad to 72 (row = 144B)
    __shared__ __align__(16) unsigned short obuf[8][16][72];    // 18 KB

    const int tid = threadIdx.x;

    // ---- one-time weight staging: fold LN affine into Wq/Wk/Wv, D^-0.5 into Wq ----
    if (tid < 256) {
        const int mat = tid >> 6, c = tid & 63;
        const float* W  = (mat == 0) ? Wq : (mat == 1) ? Wk : (mat == 2) ? Wv : Wo;
        const float* bb = (mat == 0) ? bq : (mat == 1) ? bk : (mat == 2) ? bv : bo;
        const float qs = (mat == 0) ? 0.25f : 1.0f;
        float bias = bb[c];
        for (int j = 0; j < 64; ++j) {
            float w = W[c * 64 + j];
            if (mat < 3) { bias += ln_b[j] * w; w *= ln_g[j]; }
            const int kh = j >> 5, ln = ((j >> 3) & 3) * 16 + (c & 15), i = j & 7;
            wfrag[mat * 8 + kh * 4 + (c >> 4)][ln][i] = f2bf(w * qs);
        }
        bias_s[mat][c] = bias * qs;
    }
    __syncthreads();

    const int wid = tid >> 6, lane = tid & 63;
    const int qg = lane >> 4;        // quarter / k-chunk
    const int rt = lane & 15;        // row within M-tile
    const int tok = rt & 3;          // token type of this row
    const int em  = rt >> 2;         // edge within M-tile
    const float ac = (tok == 0 || tok == 2) ? 1.f : (tok == 3) ? -1.f : 0.f;
    const float an = (tok == 0) ? 0.f : 1.f;

    // loop-invariant biases -> registers
    float biasq[4], biask[4], biasv[4], biaso[4];
    #pragma unroll
    for (int nt = 0; nt < 4; ++nt) {
        biasq[nt] = bias_s[0][nt * 16 + rt];
        biask[nt] = bias_s[1][nt * 16 + rt];
        biasv[nt] = bias_s[2][nt * 16 + rt];
        biaso[nt] = bias_s[3][nt * 16 + rt];
    }

    for (int batch = blockIdx.x; batch < NBATCH; batch += gridDim.x) {
        const int ebase = batch * 128 + wid * 16;

        // prefetch scatter targets early (hide index-load latency)
        int tg[4];
        #pragma unroll
        for (int r = 0; r < 4; ++r) tg[r] = eidx[NEDGE + ebase + qg * 4 + r];

        // ---- phase 1: build A-fragments (LN'd tokens) for 4 M-tiles = 16 edges ----
        bf16x8 af[4][2];
        #pragma unroll
        for (int m = 0; m < 4; ++m) {
            const int eg = ebase + m * 4 + em;
            const f4* pc4 = (const f4*)(x_cen + (size_t)eg * 64);
            const f4* pn4 = (const f4*)(x_nei + (size_t)eg * 64);
            f4 a0 = pc4[qg * 2], a1 = pc4[qg * 2 + 1], a2 = pc4[8 + qg * 2], a3 = pc4[8 + qg * 2 + 1];
            f4 b0 = pn4[qg * 2], b1 = pn4[qg * 2 + 1], b2 = pn4[8 + qg * 2], b3 = pn4[8 + qg * 2 + 1];
            float tv[16];
            #pragma unroll
            for (int i = 0; i < 4; ++i) {
                tv[i]      = ac * a0[i] + an * b0[i];
                tv[4 + i]  = ac * a1[i] + an * b1[i];
                tv[8 + i]  = ac * a2[i] + an * b2[i];
                tv[12 + i] = ac * a3[i] + an * b3[i];
            }
            float s = 0.f, ss = 0.f;
            #pragma unroll
            for (int i = 0; i < 16; ++i) { s += tv[i]; ss = fmaf(tv[i], tv[i], ss); }
            s  += __shfl_xor(s, 16, 64);  ss += __shfl_xor(ss, 16, 64);
            s  += __shfl_xor(s, 32, 64);  ss += __shfl_xor(ss, 32, 64);
            const float mu  = s * 0.015625f;
            const float var = fmaf(ss, 0.015625f, -mu * mu);
            const float rs  = rsqrtf(var + 1e-5f);
            const float nmrs = -mu * rs;
            #pragma unroll
            for (int kh = 0; kh < 2; ++kh) {
                union { bf16x8 v; unsigned u[4]; } pk;
                #pragma unroll
                for (int p = 0; p < 4; ++p) {
                    float lo = fmaf(tv[kh * 8 + 2 * p],     rs, nmrs);
                    float hi = fmaf(tv[kh * 8 + 2 * p + 1], rs, nmrs);
                    pk.u[p] = cvt_pk_bf16(lo, hi);
                }
                af[m][kh] = pk.v;
            }
        }

        // ---- phase 2: per output-quarter nt: q/k/v proj + softmax + PV ----
        #pragma unroll
        for (int nt = 0; nt < 4; ++nt) {
            bf16x8 wq0 = *(const bf16x8*)&wfrag[0  + nt][lane][0];
            bf16x8 wq1 = *(const bf16x8*)&wfrag[4  + nt][lane][0];
            bf16x8 wk0 = *(const bf16x8*)&wfrag[8  + nt][lane][0];
            bf16x8 wk1 = *(const bf16x8*)&wfrag[12 + nt][lane][0];
            bf16x8 wv0 = *(const bf16x8*)&wfrag[16 + nt][lane][0];
            bf16x8 wv1 = *(const bf16x8*)&wfrag[20 + nt][lane][0];
            #pragma unroll
            for (int m = 0; m < 4; ++m) {
                f32x4 aq = {biasq[nt], biasq[nt], biasq[nt], biasq[nt]};
                f32x4 ak = {biask[nt], biask[nt], biask[nt], biask[nt]};
                f32x4 av = {biasv[nt], biasv[nt], biasv[nt], biasv[nt]};
                aq = __builtin_amdgcn_mfma_f32_16x16x32_bf16(af[m][0], wq0, aq, 0, 0, 0);
                aq = __builtin_amdgcn_mfma_f32_16x16x32_bf16(af[m][1], wq1, aq, 0, 0, 0);
                ak = __builtin_amdgcn_mfma_f32_16x16x32_bf16(af[m][0], wk0, ak, 0, 0, 0);
                ak = __builtin_amdgcn_mfma_f32_16x16x32_bf16(af[m][1], wk1, ak, 0, 0, 0);
                av = __builtin_amdgcn_mfma_f32_16x16x32_bf16(af[m][0], wv0, av, 0, 0, 0);
                av = __builtin_amdgcn_mfma_f32_16x16x32_bf16(af[m][1], wv1, av, 0, 0, 0);
                // scores: q row (reg 0 = edge m*4+qg token 0) dot k rows
                float p0 = allred16(aq[0] * ak[0]);
                float p1 = allred16(aq[0] * ak[1]);
                float p2 = allred16(aq[0] * ak[2]);
                float p3 = allred16(aq[0] * ak[3]);
                // softmax without max-sub: scores bounded (|p| ~< 3), exp safe
                const float e0 = __expf(p0), e1 = __expf(p1);
                const float e2 = __expf(p2), e3 = __expf(p3);
                const float inv = __builtin_amdgcn_rcpf(e0 + e1 + e2 + e3);
                const float ov = (e0 * av[0] + e1 * av[1] + e2 * av[2] + e3 * av[3]) * inv;
                obuf[wid][m * 4 + qg][nt * 16 + rt] = f2bf(ov);   // O[edge][col]
            }
        }
        // no __syncthreads: obuf is per-wave; same-wave LDS RAW is lgkmcnt-ordered

        // ---- residual prefetch: overlap L2 latency with phase-3 LDS+MFMA ----
        float res[4][4];
        #pragma unroll
        for (int nt = 0; nt < 4; ++nt) {
            const int col = nt * 16 + rt;
            #pragma unroll
            for (int r = 0; r < 4; ++r)
                res[nt][r] = x_cen[(size_t)(ebase + qg * 4 + r) * 64 + col];
        }

        // ---- phase 3: Wo projection (all 16 rows = 16 edges valid) ----
        bf16x8 oa0 = *(const bf16x8*)&obuf[wid][rt][qg * 8];
        bf16x8 oa1 = *(const bf16x8*)&obuf[wid][rt][32 + qg * 8];
        f32x4 accO[4];
        #pragma unroll
        for (int nt = 0; nt < 4; ++nt) {
            bf16x8 wo0 = *(const bf16x8*)&wfrag[24 + nt][lane][0];
            bf16x8 wo1 = *(const bf16x8*)&wfrag[28 + nt][lane][0];
            f32x4 acc = {biaso[nt], biaso[nt], biaso[nt], biaso[nt]};
            acc = __builtin_amdgcn_mfma_f32_16x16x32_bf16(oa0, wo0, acc, 0, 0, 0);
            acc = __builtin_amdgcn_mfma_f32_16x16x32_bf16(oa1, wo1, acc, 0, 0, 0);
            accO[nt] = acc;
        }

        // ---- epilogue: residual + scatter-add (all 64 lanes active) ----
        #pragma unroll
        for (int nt = 0; nt < 4; ++nt) {
            const int col = nt * 16 + rt;
            #pragma unroll
            for (int r = 0; r < 4; ++r) {
                const float val = accO[nt][r] + res[nt][r];
                atomicAdd(outsum + (size_t)tg[r] * 64 + col, val);
            }
        }
        if (rt == 0) {
            #pragma unroll
            for (int r = 0; r < 4; ++r) atomicAdd(cnt + tg[r], 1.0f);
        }
    }
}

__global__ void nti_div(float* __restrict__ out, const float* __restrict__ cnt) {
    int i = blockIdx.x * 256 + threadIdx.x;
    if (i < NNODE * 64) {
        float c = cnt[i >> 6];
        out[i] = out[i] / fmaxf(c, 1.0f);
    }
}

extern "C" void kernel_launch(void* const* d_in, const int* in_sizes, int n_in,
                              void* d_out, int out_size, void* d_ws, size_t ws_size,
                              hipStream_t stream) {
    const float* x_cen = (const float*)d_in[0];
    const float* x_nei = (const float*)d_in[1];
    const int*   eidx  = (const int*)d_in[2];
    const float* ln_g  = (const float*)d_in[3];
    const float* ln_b  = (const float*)d_in[4];
    const float* Wq = (const float*)d_in[5];  const float* bq = (const float*)d_in[6];
    const float* Wk = (const float*)d_in[7];  const float* bk = (const float*)d_in[8];
    const float* Wv = (const float*)d_in[9];  const float* bv = (const float*)d_in[10];
    const float* Wo = (const float*)d_in[11]; const float* bo = (const float*)d_in[12];
    float* out = (float*)d_out;
    float* cnt = (float*)d_ws;

    hipMemsetAsync(d_out, 0, (size_t)NNODE * 64 * sizeof(float), stream);
    hipMemsetAsync(d_ws,  0, (size_t)NNODE * sizeof(float), stream);
    nti_main<<<512, 512, 0, stream>>>(x_cen, x_nei, eidx, ln_g, ln_b,
                                      Wq, bq, Wk, bk, Wv, bv, Wo, bo, out, cnt);
    nti_div<<<(NNODE * 64 + 255) / 256, 256, 0, stream>>>(out, cnt);
}

// Round 7
// 268.052 us; speedup vs baseline: 1.7933x; 1.0660x over previous
//
#include <hip/hip_runtime.h>
#include <hip/hip_bf16.h>

#define NEDGE 800000
#define NNODE 50000
#define NBATCH (NEDGE / 128)   // 6250 batches of 128 edges (8 waves x 16 edges)

typedef __attribute__((ext_vector_type(8))) short bf16x8;
typedef __attribute__((ext_vector_type(4))) float f32x4;
typedef __attribute__((ext_vector_type(4))) float f4;

static __device__ __forceinline__ unsigned short f2bf(float f) {
    union { float f; unsigned u; } v; v.f = f;
    unsigned r = v.u + 0x7fffu + ((v.u >> 16) & 1u);   // RNE
    return (unsigned short)(r >> 16);
}

// DPP-based sum allreduce over each 16-lane quarter (DPP "row" = 16 lanes).
template<int CTRL>
static __device__ __forceinline__ float dppadd(float x) {
    int y = __builtin_amdgcn_update_dpp(0, __builtin_bit_cast(int, x), CTRL, 0xf, 0xf, true);
    return x + __builtin_bit_cast(float, y);
}
static __device__ __forceinline__ float allred16(float x) {
    x = dppadd<0xB1>(x);    // quad_perm xor1
    x = dppadd<0x4E>(x);    // quad_perm xor2
    x = dppadd<0x141>(x);   // row_half_mirror
    x = dppadd<0x140>(x);   // row_mirror
    return x;
}

static __device__ __forceinline__ unsigned cvt_pk_bf16(float lo, float hi) {
    unsigned r;
    asm("v_cvt_pk_bf16_f32 %0, %1, %2" : "=v"(r) : "v"(lo), "v"(hi));
    return r;
}
// raw 2^x (scores pre-scaled by log2e folded into Wq/bq); |x| < ~16 here, no denorm issues
static __device__ __forceinline__ float fexp2(float x) {
    float r; asm("v_exp_f32 %0, %1" : "=v"(r) : "v"(x)); return r;
}

// Occupancy note (R2-R6 evidence): residency is 2 blocks/CU (register file incl
// MFMA acc ~128/wave -> 4 waves/SIMD). Grid MUST equal resident capacity: 512.
// (512,6) bound spills (R3, +1.1GB scratch); grid 768 makes a 2nd generation (R4).
__global__ __launch_bounds__(512, 4) void nti_main(
    const float* __restrict__ x_cen, const float* __restrict__ x_nei,
    const int* __restrict__ eidx,
    const float* __restrict__ ln_g, const float* __restrict__ ln_b,
    const float* __restrict__ Wq, const float* __restrict__ bq,
    const float* __restrict__ Wk, const float* __restrict__ bk,
    const float* __restrict__ Wv, const float* __restrict__ bv,
    const float* __restrict__ Wo, const float* __restrict__ bo,
    float* __restrict__ outsum, float* __restrict__ cnt)
{
    // B-fragments: [mat*8 + kh*4 + nt][lane][8 bf16]  (q=0,k=1,v=2,o=3)
    __shared__ __align__(16) unsigned short wfrag[32][64][8];   // 32 KB
    __shared__ float bias_s[4][64];                             // 1 KB
    // per-wave O tile: 16 rows (edges) x 64 cols, pad to 72 (row = 144B)
    __shared__ __align__(16) unsigned short obuf[8][16][72];    // 18 KB

    const int tid = threadIdx.x;

    // ---- one-time weight staging: fold LN affine into Wq/Wk/Wv; fold
    // D^-0.5 * log2(e) into Wq/bq so softmax uses raw v_exp_f32 (2^x) ----
    if (tid < 256) {
        const int mat = tid >> 6, c = tid & 63;
        const float* W  = (mat == 0) ? Wq : (mat == 1) ? Wk : (mat == 2) ? Wv : Wo;
        const float* bb = (mat == 0) ? bq : (mat == 1) ? bk : (mat == 2) ? bv : bo;
        const float qs = (mat == 0) ? 0.25f * 1.44269504f : 1.0f;
        float bias = bb[c];
        for (int j = 0; j < 64; ++j) {
            float w = W[c * 64 + j];
            if (mat < 3) { bias += ln_b[j] * w; w *= ln_g[j]; }
            const int kh = j >> 5, ln = ((j >> 3) & 3) * 16 + (c & 15), i = j & 7;
            wfrag[mat * 8 + kh * 4 + (c >> 4)][ln][i] = f2bf(w * qs);
        }
        bias_s[mat][c] = bias * qs;
    }
    __syncthreads();

    const int wid = tid >> 6, lane = tid & 63;
    const int qg = lane >> 4;        // quarter / k-chunk
    const int rt = lane & 15;        // row within M-tile
    const int tok = rt & 3;          // token type of this row
    const int em  = rt >> 2;         // edge within M-tile
    const float ac = (tok == 0 || tok == 2) ? 1.f : (tok == 3) ? -1.f : 0.f;
    const float an = (tok == 0) ? 0.f : 1.f;

    // loop-invariant biases -> registers. bk is DROPPED (softmax shift-invariant:
    // q.bk is constant over tokens). bv/bq/bo enter as post-adds (zero-C MFMAs).
    float biasq[4], biasv[4], biaso[4];
    #pragma unroll
    for (int nt = 0; nt < 4; ++nt) {
        biasq[nt] = bias_s[0][nt * 16 + rt];
        biasv[nt] = bias_s[2][nt * 16 + rt];
        biaso[nt] = bias_s[3][nt * 16 + rt];
    }
    const f32x4 vzero = {0.f, 0.f, 0.f, 0.f};   // persistent zero C operand

    for (int batch = blockIdx.x; batch < NBATCH; batch += gridDim.x) {
        const int ebase = batch * 128 + wid * 16;

        // prefetch scatter targets early (hide index-load latency)
        int tg[4];
        #pragma unroll
        for (int r = 0; r < 4; ++r) tg[r] = eidx[NEDGE + ebase + qg * 4 + r];

        // ---- phase 1: build A-fragments (LN'd tokens) for 4 M-tiles = 16 edges ----
        bf16x8 af[4][2];
        #pragma unroll
        for (int m = 0; m < 4; ++m) {
            const int eg = ebase + m * 4 + em;
            const f4* pc4 = (const f4*)(x_cen + (size_t)eg * 64);
            const f4* pn4 = (const f4*)(x_nei + (size_t)eg * 64);
            f4 a0 = pc4[qg * 2], a1 = pc4[qg * 2 + 1], a2 = pc4[8 + qg * 2], a3 = pc4[8 + qg * 2 + 1];
            f4 b0 = pn4[qg * 2], b1 = pn4[qg * 2 + 1], b2 = pn4[8 + qg * 2], b3 = pn4[8 + qg * 2 + 1];
            float tv[16];
            #pragma unroll
            for (int i = 0; i < 4; ++i) {
                tv[i]      = ac * a0[i] + an * b0[i];
                tv[4 + i]  = ac * a1[i] + an * b1[i];
                tv[8 + i]  = ac * a2[i] + an * b2[i];
                tv[12 + i] = ac * a3[i] + an * b3[i];
            }
            float s = 0.f, ss = 0.f;
            #pragma unroll
            for (int i = 0; i < 16; ++i) { s += tv[i]; ss = fmaf(tv[i], tv[i], ss); }
            s  += __shfl_xor(s, 16, 64);  ss += __shfl_xor(ss, 16, 64);
            s  += __shfl_xor(s, 32, 64);  ss += __shfl_xor(ss, 32, 64);
            const float mu  = s * 0.015625f;
            const float var = fmaf(ss, 0.015625f, -mu * mu);
            const float rs  = rsqrtf(var + 1e-5f);
            const float nmrs = -mu * rs;
            #pragma unroll
            for (int kh = 0; kh < 2; ++kh) {
                union { bf16x8 v; unsigned u[4]; } pk;
                #pragma unroll
                for (int p = 0; p < 4; ++p) {
                    float lo = fmaf(tv[kh * 8 + 2 * p],     rs, nmrs);
                    float hi = fmaf(tv[kh * 8 + 2 * p + 1], rs, nmrs);
                    pk.u[p] = cvt_pk_bf16(lo, hi);
                }
                af[m][kh] = pk.v;
            }
        }

        __builtin_amdgcn_s_setprio(1);   // MFMA/VALU-dense region; waves are independent

        // ---- phase 2: per output-quarter nt: q/k/v proj + softmax + PV ----
        #pragma unroll
        for (int nt = 0; nt < 4; ++nt) {
            bf16x8 wq0 = *(const bf16x8*)&wfrag[0  + nt][lane][0];
            bf16x8 wq1 = *(const bf16x8*)&wfrag[4  + nt][lane][0];
            bf16x8 wk0 = *(const bf16x8*)&wfrag[8  + nt][lane][0];
            bf16x8 wk1 = *(const bf16x8*)&wfrag[12 + nt][lane][0];
            bf16x8 wv0 = *(const bf16x8*)&wfrag[16 + nt][lane][0];
            bf16x8 wv1 = *(const bf16x8*)&wfrag[20 + nt][lane][0];
            #pragma unroll
            for (int m = 0; m < 4; ++m) {
                f32x4 aq = __builtin_amdgcn_mfma_f32_16x16x32_bf16(af[m][0], wq0, vzero, 0, 0, 0);
                aq = __builtin_amdgcn_mfma_f32_16x16x32_bf16(af[m][1], wq1, aq, 0, 0, 0);
                f32x4 ak = __builtin_amdgcn_mfma_f32_16x16x32_bf16(af[m][0], wk0, vzero, 0, 0, 0);
                ak = __builtin_amdgcn_mfma_f32_16x16x32_bf16(af[m][1], wk1, ak, 0, 0, 0);
                f32x4 av = __builtin_amdgcn_mfma_f32_16x16x32_bf16(af[m][0], wv0, vzero, 0, 0, 0);
                av = __builtin_amdgcn_mfma_f32_16x16x32_bf16(af[m][1], wv1, av, 0, 0, 0);
                // scores: q row (reg 0 = edge m*4+qg token 0) dot k rows, over 16 lanes
                const float q0 = aq[0] + biasq[nt];
                float p0 = allred16(q0 * ak[0]);
                float p1 = allred16(q0 * ak[1]);
                float p2 = allred16(q0 * ak[2]);
                float p3 = allred16(q0 * ak[3]);
                // softmax: no max-sub (|p| bounded); log2e pre-folded -> raw 2^x
                const float e0 = fexp2(p0), e1 = fexp2(p1);
                const float e2 = fexp2(p2), e3 = fexp2(p3);
                const float inv = __builtin_amdgcn_rcpf(e0 + e1 + e2 + e3);
                const float dot = e0 * av[0] + e1 * av[1] + e2 * av[2] + e3 * av[3];
                const float ov = fmaf(dot, inv, biasv[nt]);   // bv post-add (sum attn = 1)
                obuf[wid][m * 4 + qg][nt * 16 + rt] = (unsigned short)cvt_pk_bf16(ov, ov);
            }
        }
        // no __syncthreads: obuf is per-wave; same-wave LDS RAW is lgkmcnt-ordered

        // ---- residual prefetch (+bo fold): overlap L2 latency with phase-3 ----
        float res[4][4];
        #pragma unroll
        for (int nt = 0; nt < 4; ++nt) {
            const int col = nt * 16 + rt;
            #pragma unroll
            for (int r = 0; r < 4; ++r)
                res[nt][r] = x_cen[(size_t)(ebase + qg * 4 + r) * 64 + col] + biaso[nt];
        }

        // ---- phase 3: Wo projection (all 16 rows = 16 edges valid) ----
        bf16x8 oa0 = *(const bf16x8*)&obuf[wid][rt][qg * 8];
        bf16x8 oa1 = *(const bf16x8*)&obuf[wid][rt][32 + qg * 8];
        f32x4 accO[4];
        #pragma unroll
        for (int nt = 0; nt < 4; ++nt) {
            bf16x8 wo0 = *(const bf16x8*)&wfrag[24 + nt][lane][0];
            bf16x8 wo1 = *(const bf16x8*)&wfrag[28 + nt][lane][0];
            f32x4 acc = __builtin_amdgcn_mfma_f32_16x16x32_bf16(oa0, wo0, vzero, 0, 0, 0);
            acc = __builtin_amdgcn_mfma_f32_16x16x32_bf16(oa1, wo1, acc, 0, 0, 0);
            accO[nt] = acc;
        }
        __builtin_amdgcn_s_setprio(0);

        // ---- epilogue: residual + scatter-add (all 64 lanes active) ----
        #pragma unroll
        for (int nt = 0; nt < 4; ++nt) {
            const int col = nt * 16 + rt;
            #pragma unroll
            for (int r = 0; r < 4; ++r) {
                const float val = accO[nt][r] + res[nt][r];
                atomicAdd(outsum + (size_t)tg[r] * 64 + col, val);
            }
        }
        if (rt == 0) {
            #pragma unroll
            for (int r = 0; r < 4; ++r) atomicAdd(cnt + tg[r], 1.0f);
        }
    }
}

__global__ void nti_div(float* __restrict__ out, const float* __restrict__ cnt) {
    int i = blockIdx.x * 256 + threadIdx.x;
    if (i < NNODE * 64) {
        float c = cnt[i >> 6];
        out[i] = out[i] / fmaxf(c, 1.0f);
    }
}

extern "C" void kernel_launch(void* const* d_in, const int* in_sizes, int n_in,
                              void* d_out, int out_size, void* d_ws, size_t ws_size,
                              hipStream_t stream) {
    const float* x_cen = (const float*)d_in[0];
    const float* x_nei = (const float*)d_in[1];
    const int*   eidx  = (const int*)d_in[2];
    const float* ln_g  = (const float*)d_in[3];
    const float* ln_b  = (const float*)d_in[4];
    const float* Wq = (const float*)d_in[5];  const float* bq = (const float*)d_in[6];
    const float* Wk = (const float*)d_in[7];  const float* bk = (const float*)d_in[8];
    const float* Wv = (const float*)d_in[9];  const float* bv = (const float*)d_in[10];
    const float* Wo = (const float*)d_in[11]; const float* bo = (const float*)d_in[12];
    float* out = (float*)d_out;
    float* cnt = (float*)d_ws;

    hipMemsetAsync(d_out, 0, (size_t)NNODE * 64 * sizeof(float), stream);
    hipMemsetAsync(d_ws,  0, (size_t)NNODE * sizeof(float), stream);
    nti_main<<<512, 512, 0, stream>>>(x_cen, x_nei, eidx, ln_g, ln_b,
                                      Wq, bq, Wk, bk, Wv, bv, Wo, bo, out, cnt);
    nti_div<<<(NNODE * 64 + 255) / 256, 256, 0, stream>>>(out, cnt);
}